// Round 9
// baseline (551.335 us; speedup 1.0000x reference)
//
#include <hip/hip_runtime.h>
#include <stdint.h>

#define B_SZ   8192
#define IN_DIM 512
#define HID    256
#define PROJ   128

typedef __attribute__((ext_vector_type(8))) short bf16x8;
typedef __attribute__((ext_vector_type(4))) float f32x4;

#define GLDS16(gp, lp) __builtin_amdgcn_global_load_lds( \
    (const __attribute__((address_space(1))) void*)(gp), \
    (__attribute__((address_space(3))) void*)(lp), 16, 0, 0)

__device__ __forceinline__ unsigned short f2bf(float f) {
    union { float f; uint32_t u; } c; c.f = f;
    uint32_t u = c.u;
    uint32_t r = (u + 0x7fffu + ((u >> 16) & 1u)) >> 16;   // RNE
    return (unsigned short)r;
}
__device__ __forceinline__ float bfhi(uint32_t v) {
    union { uint32_t u; float f; } c; c.u = v & 0xffff0000u; return c.f;
}
__device__ __forceinline__ float bflo(uint32_t v) {
    union { uint32_t u; float f; } c; c.u = v << 16; return c.f;
}

// ------- K0: convert W2 to bf16 (blocks 0..2047) + transpose x to bf16 ----
__global__ __launch_bounds__(256) void k0_prep(
        const float4* __restrict__ W2, ushort4* __restrict__ W2b,
        const float* __restrict__ x, unsigned short* __restrict__ xTb) {
    __shared__ float tile[64][65];
    const int bid = blockIdx.x;
    if (bid < 2048) {
        const int nW2 = (PROJ * IN_DIM * HID) / 4;
        const int stride = 2048 * 256;
        for (int i = bid * 256 + threadIdx.x; i < nW2; i += stride) {
            float4 v = W2[i];
            ushort4 o;
            o.x = f2bf(v.x); o.y = f2bf(v.y); o.z = f2bf(v.z); o.w = f2bf(v.w);
            W2b[i] = o;
        }
    } else {
        const int tb = bid - 2048;
        const int bi = tb & 7, bb = tb >> 3;
        const int i0 = bi * 64, b0 = bb * 64;
        const int t = threadIdx.x;
        const int c = t & 63, r4 = t >> 6;
        #pragma unroll
        for (int rr = 0; rr < 64; rr += 4)
            tile[rr + r4][c] = x[(size_t)(b0 + rr + r4) * IN_DIM + i0 + c];
        __syncthreads();
        #pragma unroll
        for (int rr = 0; rr < 64; rr += 4)
            xTb[(size_t)(i0 + rr + r4) * B_SZ + b0 + c] = f2bf(tile[c][rr + r4]);
    }
}

// ---------------- K1: h = relu(ft @ W1^T + b1), bf16 out -----------------
__device__ __forceinline__ bf16x8 ld_cvt8(const float* __restrict__ s) {
    float4 a = *(const float4*)s;
    float4 b = *(const float4*)(s + 4);
    bf16x8 r;
    r[0] = (short)f2bf(a.x); r[1] = (short)f2bf(a.y);
    r[2] = (short)f2bf(a.z); r[3] = (short)f2bf(a.w);
    r[4] = (short)f2bf(b.x); r[5] = (short)f2bf(b.y);
    r[6] = (short)f2bf(b.z); r[7] = (short)f2bf(b.w);
    return r;
}

__global__ __launch_bounds__(256) void k1_hidden(
        const float* __restrict__ ft,
        const float* __restrict__ W1,
        const float* __restrict__ b1,
        unsigned short* __restrict__ hb) {
    const int lane = threadIdx.x & 63;
    const int wv   = threadIdx.x >> 6;
    const int l15  = lane & 15, q = lane >> 4;
    const int b0 = blockIdx.x * 64;
    const int n0 = wv * 64;

    f32x4 acc[4][4];
    const f32x4 z4 = {0.f, 0.f, 0.f, 0.f};
    #pragma unroll
    for (int mt = 0; mt < 4; ++mt)
        #pragma unroll
        for (int nt = 0; nt < 4; ++nt) acc[mt][nt] = z4;

    for (int kq = 0; kq < 16; ++kq) {
        const int koff = kq * 32 + q * 8;
        bf16x8 a[4], bb[4];
        #pragma unroll
        for (int mt = 0; mt < 4; ++mt)
            a[mt] = ld_cvt8(ft + (size_t)(b0 + mt*16 + l15) * IN_DIM + koff);
        #pragma unroll
        for (int nt = 0; nt < 4; ++nt)
            bb[nt] = ld_cvt8(W1 + (size_t)(n0 + nt*16 + l15) * IN_DIM + koff);
        #pragma unroll
        for (int mt = 0; mt < 4; ++mt)
            #pragma unroll
            for (int nt = 0; nt < 4; ++nt)
                acc[mt][nt] = __builtin_amdgcn_mfma_f32_16x16x32_bf16(
                    a[mt], bb[nt], acc[mt][nt], 0, 0, 0);
    }
    #pragma unroll
    for (int nt = 0; nt < 4; ++nt) {
        float bias = b1[n0 + nt*16 + l15];
        #pragma unroll
        for (int mt = 0; mt < 4; ++mt)
            #pragma unroll
            for (int r = 0; r < 4; ++r) {
                float v = acc[mt][nt][r] + bias;
                v = fmaxf(v, 0.f);
                hb[(size_t)(b0 + mt*16 + q*4 + r) * HID + n0 + nt*16 + l15] = f2bf(v);
            }
    }
}

// ---------------- K3: out[b,p] = sum_i x*(sum_k h*W2 + b2) ---------------
// Block = 4 waves x 64 b-rows = 256 rows, one p-pair. W2 tile (2p x 32i x
// 128k = 16 KB) double-buffered in LDS, stored in MFMA-FRAGMENT ORDER:
// frag f=(pp*2+sub)*4+kq is a contiguous 1 KB block, lane l's 16 B at
// f*1024 + l*16. Reads are wave-linear ds_read_b128 with immediate
// offsets -> ZERO bank conflicts, no swizzle math. Writer: wave wv stages
// frags f=wv*4+jj (pp=wv>>1, sub=wv&1, kq=jj) via global_load_lds w16.
// Single barrier per step. x bf16; b2 folded during kh=0 sweep.
__global__ __launch_bounds__(256, 3) void k3_main(
        const unsigned short* __restrict__ W2b,
        const unsigned short* __restrict__ hb,
        const unsigned short* __restrict__ xTb,
        const float* __restrict__ b2,
        float* __restrict__ out) {
    __shared__ unsigned short lbs[2][8192];   // 2 x 16 KB, frag-ordered
    const int tid  = threadIdx.x;
    const int lane = tid & 63;
    const int wv   = tid >> 6;
    const int l15  = lane & 15, q = lane >> 4;
    const int pgrp = blockIdx.x & 63;         // stride-64 => same XCD per p-pair
    const int bsup = blockIdx.x >> 6;         // 0..31
    const int p0   = pgrp * 2;
    const int b0w  = bsup * 256 + wv * 64;
    const f32x4 z4 = {0.f, 0.f, 0.f, 0.f};

    // staging source: wave wv owns (pp=wv>>1, sub=wv&1); lane l covers
    // W2 row (p0+pp)*512 + i0 + sub*16 + l15, shorts kq*32 + q*8 (+kh*128)
    const unsigned short* wrowbase =
        W2b + ((size_t)(p0 + (wv >> 1)) * IN_DIM + (wv & 1) * 16 + l15) * HID + q * 8;

    float oacc[2][4][4];
    #pragma unroll
    for (int pp = 0; pp < 2; ++pp)
        #pragma unroll
        for (int mt = 0; mt < 4; ++mt)
            #pragma unroll
            for (int r = 0; r < 4; ++r) oacc[pp][mt][r] = 0.f;

    bf16x8 afr[4][4];

    // ---- prologue: stage tile 0 (kh=0, i0=0) ----
    {
        unsigned short* Ld = &lbs[0][wv * 2048];
        #pragma unroll
        for (int jj = 0; jj < 4; ++jj)
            GLDS16(wrowbase + jj * 32, Ld + jj * 512);
    }

    #pragma unroll 1
    for (int t = 0; t < 32; ++t) {
        __syncthreads();   // drains tile-t glds; all waves done with buf[(t-1)&1]

        if (t < 31) {      // prefetch t+1 into the buffer just released
            const int tn = t + 1;
            const int kh_n = tn >> 4, i0_n = (tn & 15) * 32;
            unsigned short* Ld = &lbs[tn & 1][wv * 2048];
            const unsigned short* gs = wrowbase + (size_t)i0_n * HID + kh_n * 128;
            #pragma unroll
            for (int jj = 0; jj < 4; ++jj)
                GLDS16(gs + jj * 32, Ld + jj * 512);
        }

        const int kh = t >> 4;
        if ((t & 15) == 0) {   // load h fragments for this K-half
            #pragma unroll
            for (int mt = 0; mt < 4; ++mt) {
                const unsigned short* hrow =
                    hb + (size_t)(b0w + mt*16 + l15) * HID + kh * 128 + q * 8;
                #pragma unroll
                for (int kq = 0; kq < 4; ++kq)
                    afr[mt][kq] = *(const bf16x8*)(hrow + kq * 32);
            }
        }

        const unsigned short* Lb = &lbs[t & 1][lane * 8];   // lane-linear base
        const int i0 = (t & 15) * 32;

        #pragma unroll
        for (int sub = 0; sub < 2; ++sub) {
            const int irow = i0 + sub * 16 + l15;
            uint2 xv[4];
            const unsigned short* xp = xTb + (size_t)irow * B_SZ + b0w + q * 4;
            #pragma unroll
            for (int mt = 0; mt < 4; ++mt)
                xv[mt] = *(const uint2*)(xp + mt * 16);

            float b2v = 0.f, b2w = 0.f;
            if (kh == 0) {
                b2v = b2[p0 * 512 + irow];
                b2w = b2[(p0 + 1) * 512 + irow];
            }

            #pragma unroll
            for (int pp = 0; pp < 2; ++pp) {
                bf16x8 bfr[4];
                #pragma unroll
                for (int kq = 0; kq < 4; ++kq)
                    bfr[kq] = *(const bf16x8*)(Lb + ((pp*2 + sub)*4 + kq) * 512);

                f32x4 D[4];
                #pragma unroll
                for (int mt = 0; mt < 4; ++mt)
                    D[mt] = __builtin_amdgcn_mfma_f32_16x16x32_bf16(afr[mt][0], bfr[0], z4, 0, 0, 0);
                #pragma unroll
                for (int kq = 1; kq < 4; ++kq)
                    #pragma unroll
                    for (int mt = 0; mt < 4; ++mt)
                        D[mt] = __builtin_amdgcn_mfma_f32_16x16x32_bf16(afr[mt][kq], bfr[kq], D[mt], 0, 0, 0);

                const float bb = pp ? b2w : b2v;
                #pragma unroll
                for (int mt = 0; mt < 4; ++mt) {
                    oacc[pp][mt][0] = fmaf(D[mt][0] + bb, bflo(xv[mt].x), oacc[pp][mt][0]);
                    oacc[pp][mt][1] = fmaf(D[mt][1] + bb, bfhi(xv[mt].x), oacc[pp][mt][1]);
                    oacc[pp][mt][2] = fmaf(D[mt][2] + bb, bflo(xv[mt].y), oacc[pp][mt][2]);
                    oacc[pp][mt][3] = fmaf(D[mt][3] + bb, bfhi(xv[mt].y), oacc[pp][mt][3]);
                }
            }
        }
        // next iteration's top barrier covers buffer release + glds drain
    }

    // ---- epilogue: reduce over 16 i-lanes, store ----
    #pragma unroll
    for (int pp = 0; pp < 2; ++pp)
        #pragma unroll
        for (int mt = 0; mt < 4; ++mt)
            #pragma unroll
            for (int r = 0; r < 4; ++r) {
                float v = oacc[pp][mt][r];
                v += __shfl_xor(v, 1, 16);
                v += __shfl_xor(v, 2, 16);
                v += __shfl_xor(v, 4, 16);
                v += __shfl_xor(v, 8, 16);
                if (l15 == 0)
                    out[(size_t)(b0w + mt*16 + q*4 + r) * PROJ + p0 + pp] = v;
            }
}

extern "C" void kernel_launch(void* const* d_in, const int* in_sizes, int n_in,
                              void* d_out, int out_size, void* d_ws, size_t ws_size,
                              hipStream_t stream) {
    const float* ft = (const float*)d_in[0];
    const float* x  = (const float*)d_in[1];
    const float* W1 = (const float*)d_in[2];
    const float* b1 = (const float*)d_in[3];
    const float* W2 = (const float*)d_in[4];
    const float* b2 = (const float*)d_in[5];
    float* out = (float*)d_out;

    char* ws = (char*)d_ws;
    unsigned short* W2b = (unsigned short*)(ws);             // 33,554,432 B
    unsigned short* hb  = (unsigned short*)(ws + 33554432);  //  4,194,304 B
    unsigned short* xTb = (unsigned short*)(ws + 37748736);  //  8,388,608 B

    hipLaunchKernelGGL(k0_prep, dim3(3072), dim3(256), 0, stream,
        (const float4*)W2, (ushort4*)W2b, x, xTb);
    hipLaunchKernelGGL(k1_hidden, dim3(128), dim3(256), 0, stream, ft, W1, b1, hb);
    hipLaunchKernelGGL(k3_main, dim3(2048), dim3(256), 0, stream, W2b, hb, xTb, b2, out);
}